// Round 2
// baseline (265.551 us; speedup 1.0000x reference)
//
#include <hip/hip_runtime.h>
#include <math.h>

#define N_NODES 2048
#define N_EDGES 65536
#define SEQL 5
#define IN_F 32
#define HID 64
#define OUT_F 16
#define LN_EPS 1e-5f

// ---------------- degree + in-edge count scatter ----------------
__global__ void k_deg(const int* __restrict__ ei, const float* __restrict__ ew,
                      float* __restrict__ deg, int* __restrict__ cnt){
    int e = blockIdx.x * 256 + threadIdx.x;
    if (e < N_EDGES){
        int d = ei[N_EDGES + e];
        atomicAdd(&deg[d], ew[e]);
        atomicAdd(&cnt[d], 1);
    }
}

// ---------------- dinv/dself + rowptr scan + combined gate weights ----------------
__global__ void k_scan_wcomb(const float* __restrict__ deg, const int* __restrict__ cnt,
                             float* __restrict__ dinv, float* __restrict__ dself, int* __restrict__ rowptr,
                             const float* __restrict__ Wcz, const float* __restrict__ Wlz,
                             const float* __restrict__ bcz, const float* __restrict__ blz,
                             const float* __restrict__ Wch, const float* __restrict__ Wlh,
                             const float* __restrict__ bch, const float* __restrict__ blh,
                             float* __restrict__ Wzp, float* __restrict__ Whp, float* __restrict__ bUV){
    int b = blockIdx.x, t = threadIdx.x;
    if (b == 0){
        __shared__ int s[1024];
        int n0 = 2*t, n1 = 2*t + 1;
        float d0 = deg[n0] + 1.f, d1 = deg[n1] + 1.f;
        float i0 = 1.f / sqrtf(d0), i1 = 1.f / sqrtf(d1);
        dinv[n0] = i0; dinv[n1] = i1;
        dself[n0] = i0*i0; dself[n1] = i1*i1;
        int a0 = cnt[n0], a1 = cnt[n1];
        s[t] = a0 + a1;
        __syncthreads();
        for (int off = 1; off < 1024; off <<= 1){
            int v = (t >= off) ? s[t - off] : 0;
            __syncthreads();
            s[t] += v;
            __syncthreads();
        }
        int pe = (t == 0) ? 0 : s[t-1];
        rowptr[n0] = pe;
        rowptr[n1] = pe + a0;
        if (t == 1023) rowptr[2048] = s[1023];
    } else {
        const float* Wc = (b == 1) ? Wcz : Wch;
        const float* Wl = (b == 1) ? Wlz : Wlh;
        const float* bc = (b == 1) ? bcz : bch;
        const float* bl = (b == 1) ? blz : blh;
        float* Wp = (b == 1) ? Wzp : Whp;
        for (int idx = t; idx < IN_F*HID; idx += 1024){
            int i = idx >> 6, f = idx & 63;
            float s = 0.f;
            for (int k = 0; k < HID; ++k) s += Wc[i*HID+k] * Wl[k*HID+f];
            Wp[idx] = s;
        }
        if (t < HID){
            float s = bl[t];
            for (int k = 0; k < HID; ++k) s += bc[k] * Wl[k*HID+t];
            bUV[(b-1)*HID + t] = s;
        }
    }
}

// ---------------- CSR fill + per-edge norm ----------------
__global__ void k_csr(const int* __restrict__ ei, const float* __restrict__ ew,
                      const float* __restrict__ dinv, const int* __restrict__ rowptr,
                      int* __restrict__ fill, int* __restrict__ csrc, float* __restrict__ cnrm){
    int e = blockIdx.x * 256 + threadIdx.x;
    if (e < N_EDGES){
        int s = ei[e], d = ei[N_EDGES + e];
        int pos = rowptr[d] + atomicAdd(&fill[d], 1);
        csrc[pos] = s;
        cnrm[pos] = dinv[s] * ew[e] * dinv[d];
    }
}

// ---------------- U = x@Wzp, V = x@Whp over all (t,n) rows ----------------
__global__ void k_uv(const float* __restrict__ x, const float* __restrict__ Wzp,
                     const float* __restrict__ Whp, float* __restrict__ U, float* __restrict__ V){
    int r = blockIdx.x;           // 0..SEQL*N_NODES
    int t = threadIdx.x;          // 0..127
    __shared__ float xs[IN_F];
    if (t < IN_F) xs[t] = x[r*IN_F + t];
    __syncthreads();
    int f = t & 63;
    const float* W = (t < 64) ? Wzp : Whp;
    float* O = (t < 64) ? U : V;
    float s = 0.f;
    #pragma unroll
    for (int i = 0; i < IN_F; ++i) s += xs[i] * W[i*HID + f];
    O[r*HID + f] = s;
}

// ---------------- per-node: aggregate gates over 5 steps, Wred-reduce, emb products ----------------
__global__ void k_gate(const float* __restrict__ U, const float* __restrict__ V, const float* __restrict__ bUV,
                       const float* __restrict__ dself, const int* __restrict__ rowptr,
                       const int* __restrict__ csrc, const float* __restrict__ cnrm,
                       const float* __restrict__ Wred, const float* __restrict__ bred,
                       const float* __restrict__ Wi1, const float* __restrict__ bi1, const float* __restrict__ Wc1,
                       float* __restrict__ emb, float* __restrict__ ag, float* __restrict__ bjp,
                       float* __restrict__ hw1){
    int n = blockIdx.x, f = threadIdx.x;
    __shared__ float hs[HID];
    float ds = dself[n];
    int beg = rowptr[n], end = rowptr[n+1];
    float bu = bUV[f], bv = bUV[HID + f];
    float hred = bred[f];
    for (int t = 0; t < SEQL; ++t){
        float au = 0.f, av = 0.f;
        for (int p = beg; p < end; ++p){
            int s = csrc[p]; float nr = cnrm[p];
            au += nr * U[(t*N_NODES + s)*HID + f];
            av += nr * V[(t*N_NODES + s)*HID + f];
        }
        float zz = au + ds * U[(t*N_NODES + n)*HID + f] + bu;
        float hh = av + ds * V[(t*N_NODES + n)*HID + f] + bv;
        float z = 1.f / (1.f + expf(-zz));
        float h = (1.f - z) * tanhf(hh);
        hs[f] = h;
        __syncthreads();
        #pragma unroll
        for (int k = 0; k < HID; ++k) hred += hs[k] * Wred[(t*HID + k)*HID + f];
        __syncthreads();
    }
    emb[n*HID + f] = hred;
    hs[f] = hred;
    __syncthreads();
    float aa = 0.f, bb = bi1[f], hw = 0.f;
    #pragma unroll
    for (int k = 0; k < HID; ++k){
        float ev = hs[k];
        aa += ev * Wi1[k*HID + f];
        bb += ev * Wi1[(HID + k)*HID + f];
        hw += ev * Wc1[k*HID + f];
    }
    ag[n*HID + f] = aa;
    bjp[n*HID + f] = bb;    // bi1 folded in
    hw1[n*HID + f] = hw;
}

// ---------------- gcn1 aggregate + LN + relu + pre-multiply Wc2 ----------------
__global__ void k_gcn1(const float* __restrict__ hw1, const float* __restrict__ dself,
                       const int* __restrict__ rowptr, const int* __restrict__ csrc, const float* __restrict__ cnrm,
                       const float* __restrict__ bc1, const float* __restrict__ g1, const float* __restrict__ be1,
                       const float* __restrict__ Wc2, float* __restrict__ hw2){
    int n = blockIdx.x, f = threadIdx.x;
    int beg = rowptr[n], end = rowptr[n+1];
    float agg = 0.f;
    for (int p = beg; p < end; ++p) agg += cnrm[p] * hw1[csrc[p]*HID + f];
    float g = agg + dself[n] * hw1[n*HID + f] + bc1[f];
    float sum = g;
    for (int o = 32; o > 0; o >>= 1) sum += __shfl_xor(sum, o, 64);
    float mu = sum * (1.f/64.f);
    float d = g - mu;
    float vs = d * d;
    for (int o = 32; o > 0; o >>= 1) vs += __shfl_xor(vs, o, 64);
    float var = vs * (1.f/64.f);
    float h = d * (1.f / sqrtf(var + LN_EPS)) * g1[f] + be1[f];
    h = fmaxf(h, 0.f);
    __shared__ float hsh[HID];
    hsh[f] = h;
    __syncthreads();
    float s = 0.f;
    #pragma unroll
    for (int k = 0; k < HID; ++k) s += hsh[k] * Wc2[k*HID + f];
    hw2[n*HID + f] = s;
}

// ---------------- gcn2 aggregate + LN + relu + node_pred output ----------------
__global__ void k_gcn2(const float* __restrict__ hw2, const float* __restrict__ dself,
                       const int* __restrict__ rowptr, const int* __restrict__ csrc, const float* __restrict__ cnrm,
                       const float* __restrict__ bc2, const float* __restrict__ g2, const float* __restrict__ be2,
                       const float* __restrict__ Wout, const float* __restrict__ bout, float* __restrict__ outp){
    int n = blockIdx.x, f = threadIdx.x;
    int beg = rowptr[n], end = rowptr[n+1];
    float agg = 0.f;
    for (int p = beg; p < end; ++p) agg += cnrm[p] * hw2[csrc[p]*HID + f];
    float g = agg + dself[n] * hw2[n*HID + f] + bc2[f];
    float sum = g;
    for (int o = 32; o > 0; o >>= 1) sum += __shfl_xor(sum, o, 64);
    float mu = sum * (1.f/64.f);
    float d = g - mu;
    float vs = d * d;
    for (int o = 32; o > 0; o >>= 1) vs += __shfl_xor(vs, o, 64);
    float var = vs * (1.f/64.f);
    float h = d * (1.f / sqrtf(var + LN_EPS)) * g2[f] + be2[f];
    h = fmaxf(h, 0.f);
    __shared__ float hsh[HID];
    hsh[f] = h;
    __syncthreads();
    if (f < OUT_F){
        float s = bout[f];
        #pragma unroll
        for (int k = 0; k < HID; ++k) s += hsh[k] * Wout[k*OUT_F + f];
        outp[n*OUT_F + f] = s;
    }
}

// ---------------- scores[i,j] = sum_f relu(a_i + bj_j)_f * Wi2_f + bi2 ----------------
__global__ __launch_bounds__(256) void k_scores(const float* __restrict__ ag, const float* __restrict__ bjp,
                         const float* __restrict__ Wi2, const float* __restrict__ bi2,
                         float* __restrict__ outs){
    __shared__ float bs[64*65];
    __shared__ float wv[64];
    int tid = threadIdx.x;
    int j0 = blockIdx.x * 64;
    int i0 = blockIdx.y * 16;
    for (int idx = tid; idx < 4096; idx += 256){
        int jj = idx >> 6, f = idx & 63;
        bs[jj*65 + f] = bjp[(j0 + jj)*HID + f];
    }
    if (tid < 64) wv[tid] = Wi2[tid];
    __syncthreads();
    int tj = tid & 63;
    int w = __builtin_amdgcn_readfirstlane(tid >> 6);   // wave-uniform wave id -> scalar a-loads
    const float* ar = ag + (i0 + w*4)*HID;
    float bi2v = bi2[0];
    float acc0 = 0.f, acc1 = 0.f, acc2 = 0.f, acc3 = 0.f;
    #pragma unroll
    for (int f = 0; f < 64; ++f){
        float bv = bs[tj*65 + f];
        float wf = wv[f];
        acc0 += fmaxf(ar[       f] + bv, 0.f) * wf;
        acc1 += fmaxf(ar[ 64 +  f] + bv, 0.f) * wf;
        acc2 += fmaxf(ar[128 +  f] + bv, 0.f) * wf;
        acc3 += fmaxf(ar[192 +  f] + bv, 0.f) * wf;
    }
    long ro = (long)(i0 + w*4) * N_NODES + j0 + tj;
    outs[ro                ] = acc0 + bi2v;
    outs[ro +     N_NODES  ] = acc1 + bi2v;
    outs[ro + 2L* N_NODES  ] = acc2 + bi2v;
    outs[ro + 3L* N_NODES  ] = acc3 + bi2v;
}

extern "C" void kernel_launch(void* const* d_in, const int* in_sizes, int n_in,
                              void* d_out, int out_size, void* d_ws, size_t ws_size,
                              hipStream_t stream){
    const float* x   = (const float*)d_in[0];
    const float* ew  = (const float*)d_in[1];
    const float* Wcz = (const float*)d_in[2];  const float* bcz = (const float*)d_in[3];
    const float* Wlz = (const float*)d_in[4];  const float* blz = (const float*)d_in[5];
    // d_in[6..9]: Wcr/bcr/Wlr/blr — dead code (H=0 so reset gate has no effect)
    const float* Wch = (const float*)d_in[10]; const float* bch = (const float*)d_in[11];
    const float* Wlh = (const float*)d_in[12]; const float* blh = (const float*)d_in[13];
    const float* Wred= (const float*)d_in[14]; const float* bred= (const float*)d_in[15];
    const float* Wc1 = (const float*)d_in[16]; const float* bc1 = (const float*)d_in[17];
    const float* Wc2 = (const float*)d_in[18]; const float* bc2 = (const float*)d_in[19];
    const float* g1  = (const float*)d_in[20]; const float* be1 = (const float*)d_in[21];
    const float* g2  = (const float*)d_in[22]; const float* be2 = (const float*)d_in[23];
    const float* Wout= (const float*)d_in[24]; const float* bout= (const float*)d_in[25];
    const float* Wi1 = (const float*)d_in[26]; const float* bi1 = (const float*)d_in[27];
    const float* Wi2 = (const float*)d_in[28]; const float* bi2 = (const float*)d_in[29];
    const int*  ei  = (const int*)d_in[30];

    char* w = (char*)d_ws;
    float* deg    = (float*)(w + 0);        // 2048 f
    int*   cnt    = (int*)  (w + 8192);     // 2048 i
    int*   fill   = (int*)  (w + 16384);    // 2048 i   [first 24576 B memset to 0]
    int*   rowptr = (int*)  (w + 24576);    // 2049 i
    float* dinv   = (float*)(w + 36864);
    float* dself  = (float*)(w + 45056);
    int*   csrc   = (int*)  (w + 53248);    // E ints
    float* cnrm   = (float*)(w + 315392);   // E floats
    float* Wzp    = (float*)(w + 577536);   // 32*64
    float* Whp    = (float*)(w + 585728);   // 32*64
    float* bUV    = (float*)(w + 593920);   // 128
    float* U      = (float*)(w + 595968);              // 5N*64
    float* V      = (float*)(w + 595968 + 2621440);    // 5N*64
    float* emb    = (float*)(w + 595968 + 2*2621440);  // N*64
    float* ag     = emb + N_NODES*HID;
    float* bjp    = ag  + N_NODES*HID;
    float* hw1    = bjp + N_NODES*HID;
    float* hw2    = hw1 + N_NODES*HID;

    hipMemsetAsync(d_ws, 0, 24576, stream);
    k_deg<<<N_EDGES/256, 256, 0, stream>>>(ei, ew, deg, cnt);
    k_scan_wcomb<<<3, 1024, 0, stream>>>(deg, cnt, dinv, dself, rowptr,
                                         Wcz, Wlz, bcz, blz, Wch, Wlh, bch, blh,
                                         Wzp, Whp, bUV);
    k_csr<<<N_EDGES/256, 256, 0, stream>>>(ei, ew, dinv, rowptr, fill, csrc, cnrm);
    k_uv<<<SEQL*N_NODES, 128, 0, stream>>>(x, Wzp, Whp, U, V);
    k_gate<<<N_NODES, 64, 0, stream>>>(U, V, bUV, dself, rowptr, csrc, cnrm,
                                       Wred, bred, Wi1, bi1, Wc1,
                                       emb, ag, bjp, hw1);
    k_gcn1<<<N_NODES, 64, 0, stream>>>(hw1, dself, rowptr, csrc, cnrm, bc1, g1, be1, Wc2, hw2);
    k_gcn2<<<N_NODES, 64, 0, stream>>>(hw2, dself, rowptr, csrc, cnrm, bc2, g2, be2, Wout, bout,
                                       (float*)d_out);
    dim3 sg(N_NODES/64, N_NODES/16);
    k_scores<<<sg, 256, 0, stream>>>(ag, bjp, Wi2, bi2, (float*)d_out + N_NODES*OUT_F);
}

// Round 3
// 231.750 us; speedup vs baseline: 1.1458x; 1.1458x over previous
//
#include <hip/hip_runtime.h>
#include <math.h>

#define N_NODES 2048
#define N_EDGES 65536
#define SEQL 5
#define IN_F 32
#define HID 64
#define OUT_F 16
#define LN_EPS 1e-5f

// ---------------- degree + in-edge count scatter ----------------
__global__ void k_deg(const int* __restrict__ ei, const float* __restrict__ ew,
                      float* __restrict__ deg, int* __restrict__ cnt){
    int e = blockIdx.x * 256 + threadIdx.x;
    if (e < N_EDGES){
        int d = ei[N_EDGES + e];
        atomicAdd(&deg[d], ew[e]);
        atomicAdd(&cnt[d], 1);
    }
}

// ---------------- dinv/dself + rowptr scan + combined gate weights ----------------
__global__ void k_scan_wcomb(const float* __restrict__ deg, const int* __restrict__ cnt,
                             float* __restrict__ dinv, float* __restrict__ dself, int* __restrict__ rowptr,
                             const float* __restrict__ Wcz, const float* __restrict__ Wlz,
                             const float* __restrict__ bcz, const float* __restrict__ blz,
                             const float* __restrict__ Wch, const float* __restrict__ Wlh,
                             const float* __restrict__ bch, const float* __restrict__ blh,
                             float* __restrict__ Wzp, float* __restrict__ Whp, float* __restrict__ bUV){
    int b = blockIdx.x, t = threadIdx.x;
    if (b == 0){
        __shared__ int s[1024];
        int n0 = 2*t, n1 = 2*t + 1;
        float d0 = deg[n0] + 1.f, d1 = deg[n1] + 1.f;
        float i0 = 1.f / sqrtf(d0), i1 = 1.f / sqrtf(d1);
        dinv[n0] = i0; dinv[n1] = i1;
        dself[n0] = i0*i0; dself[n1] = i1*i1;
        int a0 = cnt[n0], a1 = cnt[n1];
        s[t] = a0 + a1;
        __syncthreads();
        for (int off = 1; off < 1024; off <<= 1){
            int v = (t >= off) ? s[t - off] : 0;
            __syncthreads();
            s[t] += v;
            __syncthreads();
        }
        int pe = (t == 0) ? 0 : s[t-1];
        rowptr[n0] = pe;
        rowptr[n1] = pe + a0;
        if (t == 1023) rowptr[2048] = s[1023];
    } else {
        const float* Wc = (b == 1) ? Wcz : Wch;
        const float* Wl = (b == 1) ? Wlz : Wlh;
        const float* bc = (b == 1) ? bcz : bch;
        const float* bl = (b == 1) ? blz : blh;
        float* Wp = (b == 1) ? Wzp : Whp;
        for (int idx = t; idx < IN_F*HID; idx += 1024){
            int i = idx >> 6, f = idx & 63;
            float s = 0.f;
            for (int k = 0; k < HID; ++k) s += Wc[i*HID+k] * Wl[k*HID+f];
            Wp[idx] = s;
        }
        if (t < HID){
            float s = bl[t];
            for (int k = 0; k < HID; ++k) s += bc[k] * Wl[k*HID+t];
            bUV[(b-1)*HID + t] = s;
        }
    }
}

// ---------------- CSR fill + per-edge norm ----------------
__global__ void k_csr(const int* __restrict__ ei, const float* __restrict__ ew,
                      const float* __restrict__ dinv, const int* __restrict__ rowptr,
                      int* __restrict__ fill, int* __restrict__ csrc, float* __restrict__ cnrm){
    int e = blockIdx.x * 256 + threadIdx.x;
    if (e < N_EDGES){
        int s = ei[e], d = ei[N_EDGES + e];
        int pos = rowptr[d] + atomicAdd(&fill[d], 1);
        csrc[pos] = s;
        cnrm[pos] = dinv[s] * ew[e] * dinv[d];
    }
}

// ---------------- U = x@Wzp, V = x@Whp over all (t,n) rows ----------------
__global__ void k_uv(const float* __restrict__ x, const float* __restrict__ Wzp,
                     const float* __restrict__ Whp, float* __restrict__ U, float* __restrict__ V){
    int r = blockIdx.x;           // 0..SEQL*N_NODES
    int t = threadIdx.x;          // 0..127
    __shared__ float xs[IN_F];
    if (t < IN_F) xs[t] = x[r*IN_F + t];
    __syncthreads();
    int f = t & 63;
    const float* W = (t < 64) ? Wzp : Whp;
    float* O = (t < 64) ? U : V;
    float s = 0.f;
    #pragma unroll
    for (int i = 0; i < IN_F; ++i) s += xs[i] * W[i*HID + f];
    O[r*HID + f] = s;
}

// ---------------- per-node gates: wave t = timestep t (5 waves/block) ----------------
__global__ __launch_bounds__(320) void k_gate(
                       const float* __restrict__ U, const float* __restrict__ V, const float* __restrict__ bUV,
                       const float* __restrict__ dself, const int* __restrict__ rowptr,
                       const int* __restrict__ csrc, const float* __restrict__ cnrm,
                       const float* __restrict__ Wred, const float* __restrict__ bred,
                       const float* __restrict__ Wi1, const float* __restrict__ bi1, const float* __restrict__ Wc1,
                       float* __restrict__ emb, float* __restrict__ ag, float* __restrict__ bjp,
                       float* __restrict__ hw1){
    int n = blockIdx.x;
    int f = threadIdx.x & 63;
    int t = threadIdx.x >> 6;              // 0..4 : timestep handled by this wave
    __shared__ float hs[SEQL][HID];
    __shared__ float part[SEQL][HID];
    float ds = dself[n];
    int beg = rowptr[n], end = rowptr[n+1];
    const float* Ut = U + (size_t)t * N_NODES * HID;
    const float* Vt = V + (size_t)t * N_NODES * HID;
    float au = 0.f, av = 0.f;
    int p = beg;
    for (; p + 1 < end; p += 2){           // unroll x2: 4 gathers in flight
        int   s0 = csrc[p],  s1 = csrc[p+1];
        float n0 = cnrm[p],  n1 = cnrm[p+1];
        float u0 = Ut[s0*HID+f], u1 = Ut[s1*HID+f];
        float v0 = Vt[s0*HID+f], v1 = Vt[s1*HID+f];
        au += n0*u0 + n1*u1;
        av += n0*v0 + n1*v1;
    }
    if (p < end){
        int s0 = csrc[p]; float n0 = cnrm[p];
        au += n0 * Ut[s0*HID+f];
        av += n0 * Vt[s0*HID+f];
    }
    float zz = au + ds * Ut[n*HID+f] + bUV[f];
    float hh = av + ds * Vt[n*HID+f] + bUV[HID+f];
    float z = 1.f / (1.f + expf(-zz));
    hs[t][f] = (1.f - z) * tanhf(hh);
    __syncthreads();
    // partial Wred: each wave contracts its own timestep's 64 k's
    float pp = 0.f;
    #pragma unroll
    for (int k = 0; k < HID; ++k) pp += hs[t][k] * Wred[(t*HID + k)*HID + f];
    part[t][f] = pp;
    __syncthreads();
    if (t == 0){
        float hred = bred[f] + part[0][f] + part[1][f] + part[2][f] + part[3][f] + part[4][f];
        emb[n*HID + f] = hred;
        hs[0][f] = hred;
    }
    __syncthreads();
    // waves 0/1/2 compute the three 64x64 products off the embedding
    if (t < 3){
        const float* W = (t == 0) ? Wi1 : (t == 1) ? (Wi1 + HID*HID) : Wc1;
        float acc = (t == 1) ? bi1[f] : 0.f;
        #pragma unroll
        for (int k = 0; k < HID; ++k) acc += hs[0][k] * W[k*HID + f];
        float* O = (t == 0) ? ag : (t == 1) ? bjp : hw1;
        O[n*HID + f] = acc;                // bjp has bi1 folded in
    }
}

// ---------------- gcn1: 4 waves split edges, LN+relu, premultiply Wc2 ----------------
__global__ __launch_bounds__(256) void k_gcn1(
                       const float* __restrict__ hw1, const float* __restrict__ dself,
                       const int* __restrict__ rowptr, const int* __restrict__ csrc, const float* __restrict__ cnrm,
                       const float* __restrict__ bc1, const float* __restrict__ g1, const float* __restrict__ be1,
                       const float* __restrict__ Wc2, float* __restrict__ hw2){
    int n = blockIdx.x;
    int f = threadIdx.x & 63;
    int w = threadIdx.x >> 6;              // 0..3
    int beg = rowptr[n], end = rowptr[n+1];
    __shared__ float red[4][HID];
    __shared__ float hsh[HID];
    float agg = 0.f;
    for (int p = beg + w; p < end; p += 4) agg += cnrm[p] * hw1[csrc[p]*HID + f];
    red[w][f] = agg;
    __syncthreads();
    if (w == 0){
        float g = red[0][f] + red[1][f] + red[2][f] + red[3][f]
                + dself[n] * hw1[n*HID + f] + bc1[f];
        float sum = g;
        for (int o = 32; o > 0; o >>= 1) sum += __shfl_xor(sum, o, 64);
        float mu = sum * (1.f/64.f);
        float d = g - mu;
        float vs = d * d;
        for (int o = 32; o > 0; o >>= 1) vs += __shfl_xor(vs, o, 64);
        float var = vs * (1.f/64.f);
        float h = d * (1.f / sqrtf(var + LN_EPS)) * g1[f] + be1[f];
        hsh[f] = fmaxf(h, 0.f);
    }
    __syncthreads();
    float s = 0.f;
    #pragma unroll
    for (int k = 0; k < 16; ++k) s += hsh[w*16 + k] * Wc2[(w*16 + k)*HID + f];
    red[w][f] = s;
    __syncthreads();
    if (w == 0) hw2[n*HID + f] = red[0][f] + red[1][f] + red[2][f] + red[3][f];
}

// ---------------- gcn2: 4 waves split edges, LN+relu, node_pred out ----------------
__global__ __launch_bounds__(256) void k_gcn2(
                       const float* __restrict__ hw2, const float* __restrict__ dself,
                       const int* __restrict__ rowptr, const int* __restrict__ csrc, const float* __restrict__ cnrm,
                       const float* __restrict__ bc2, const float* __restrict__ g2, const float* __restrict__ be2,
                       const float* __restrict__ Wout, const float* __restrict__ bout, float* __restrict__ outp){
    int n = blockIdx.x;
    int f = threadIdx.x & 63;
    int w = threadIdx.x >> 6;
    int beg = rowptr[n], end = rowptr[n+1];
    __shared__ float red[4][HID];
    __shared__ float hsh[HID];
    float agg = 0.f;
    for (int p = beg + w; p < end; p += 4) agg += cnrm[p] * hw2[csrc[p]*HID + f];
    red[w][f] = agg;
    __syncthreads();
    if (w == 0){
        float g = red[0][f] + red[1][f] + red[2][f] + red[3][f]
                + dself[n] * hw2[n*HID + f] + bc2[f];
        float sum = g;
        for (int o = 32; o > 0; o >>= 1) sum += __shfl_xor(sum, o, 64);
        float mu = sum * (1.f/64.f);
        float d = g - mu;
        float vs = d * d;
        for (int o = 32; o > 0; o >>= 1) vs += __shfl_xor(vs, o, 64);
        float var = vs * (1.f/64.f);
        float h = d * (1.f / sqrtf(var + LN_EPS)) * g2[f] + be2[f];
        hsh[f] = fmaxf(h, 0.f);
    }
    __syncthreads();
    if (w == 0 && f < OUT_F){
        float s = bout[f];
        #pragma unroll
        for (int k = 0; k < HID; ++k) s += hsh[k] * Wout[k*OUT_F + f];
        outp[n*OUT_F + f] = s;
    }
}

// ---------------- scores[i,j] = sum_f relu(a_i + bj_j)_f * Wi2_f + bi2 ----------------
__global__ __launch_bounds__(256) void k_scores(const float* __restrict__ ag, const float* __restrict__ bjp,
                         const float* __restrict__ Wi2, const float* __restrict__ bi2,
                         float* __restrict__ outs){
    __shared__ float bs[64*65];
    __shared__ float wv[64];
    int tid = threadIdx.x;
    int j0 = blockIdx.x * 64;
    int i0 = blockIdx.y * 16;
    for (int idx = tid; idx < 4096; idx += 256){
        int jj = idx >> 6, f = idx & 63;
        bs[jj*65 + f] = bjp[(j0 + jj)*HID + f];
    }
    if (tid < 64) wv[tid] = Wi2[tid];
    __syncthreads();
    int tj = tid & 63;
    int w = __builtin_amdgcn_readfirstlane(tid >> 6);   // wave-uniform wave id -> scalar a-loads
    const float* ar = ag + (i0 + w*4)*HID;
    float bi2v = bi2[0];
    float acc0 = 0.f, acc1 = 0.f, acc2 = 0.f, acc3 = 0.f;
    #pragma unroll
    for (int f = 0; f < 64; ++f){
        float bv = bs[tj*65 + f];
        float wf = wv[f];
        acc0 += fmaxf(ar[       f] + bv, 0.f) * wf;
        acc1 += fmaxf(ar[ 64 +  f] + bv, 0.f) * wf;
        acc2 += fmaxf(ar[128 +  f] + bv, 0.f) * wf;
        acc3 += fmaxf(ar[192 +  f] + bv, 0.f) * wf;
    }
    long ro = (long)(i0 + w*4) * N_NODES + j0 + tj;
    outs[ro                ] = acc0 + bi2v;
    outs[ro +     N_NODES  ] = acc1 + bi2v;
    outs[ro + 2L* N_NODES  ] = acc2 + bi2v;
    outs[ro + 3L* N_NODES  ] = acc3 + bi2v;
}

extern "C" void kernel_launch(void* const* d_in, const int* in_sizes, int n_in,
                              void* d_out, int out_size, void* d_ws, size_t ws_size,
                              hipStream_t stream){
    const float* x   = (const float*)d_in[0];
    const float* ew  = (const float*)d_in[1];
    const float* Wcz = (const float*)d_in[2];  const float* bcz = (const float*)d_in[3];
    const float* Wlz = (const float*)d_in[4];  const float* blz = (const float*)d_in[5];
    // d_in[6..9]: Wcr/bcr/Wlr/blr — dead code (H=0 so reset gate has no effect)
    const float* Wch = (const float*)d_in[10]; const float* bch = (const float*)d_in[11];
    const float* Wlh = (const float*)d_in[12]; const float* blh = (const float*)d_in[13];
    const float* Wred= (const float*)d_in[14]; const float* bred= (const float*)d_in[15];
    const float* Wc1 = (const float*)d_in[16]; const float* bc1 = (const float*)d_in[17];
    const float* Wc2 = (const float*)d_in[18]; const float* bc2 = (const float*)d_in[19];
    const float* g1  = (const float*)d_in[20]; const float* be1 = (const float*)d_in[21];
    const float* g2  = (const float*)d_in[22]; const float* be2 = (const float*)d_in[23];
    const float* Wout= (const float*)d_in[24]; const float* bout= (const float*)d_in[25];
    const float* Wi1 = (const float*)d_in[26]; const float* bi1 = (const float*)d_in[27];
    const float* Wi2 = (const float*)d_in[28]; const float* bi2 = (const float*)d_in[29];
    const int*  ei  = (const int*)d_in[30];

    char* w = (char*)d_ws;
    float* deg    = (float*)(w + 0);        // 2048 f
    int*   cnt    = (int*)  (w + 8192);     // 2048 i
    int*   fill   = (int*)  (w + 16384);    // 2048 i   [first 24576 B memset to 0]
    int*   rowptr = (int*)  (w + 24576);    // 2049 i
    float* dinv   = (float*)(w + 36864);
    float* dself  = (float*)(w + 45056);
    int*   csrc   = (int*)  (w + 53248);    // E ints
    float* cnrm   = (float*)(w + 315392);   // E floats
    float* Wzp    = (float*)(w + 577536);   // 32*64
    float* Whp    = (float*)(w + 585728);   // 32*64
    float* bUV    = (float*)(w + 593920);   // 128
    float* U      = (float*)(w + 595968);              // 5N*64
    float* V      = (float*)(w + 595968 + 2621440);    // 5N*64
    float* emb    = (float*)(w + 595968 + 2*2621440);  // N*64
    float* ag     = emb + N_NODES*HID;
    float* bjp    = ag  + N_NODES*HID;
    float* hw1    = bjp + N_NODES*HID;
    float* hw2    = hw1 + N_NODES*HID;

    hipMemsetAsync(d_ws, 0, 24576, stream);
    k_deg<<<N_EDGES/256, 256, 0, stream>>>(ei, ew, deg, cnt);
    k_scan_wcomb<<<3, 1024, 0, stream>>>(deg, cnt, dinv, dself, rowptr,
                                         Wcz, Wlz, bcz, blz, Wch, Wlh, bch, blh,
                                         Wzp, Whp, bUV);
    k_csr<<<N_EDGES/256, 256, 0, stream>>>(ei, ew, dinv, rowptr, fill, csrc, cnrm);
    k_uv<<<SEQL*N_NODES, 128, 0, stream>>>(x, Wzp, Whp, U, V);
    k_gate<<<N_NODES, 320, 0, stream>>>(U, V, bUV, dself, rowptr, csrc, cnrm,
                                        Wred, bred, Wi1, bi1, Wc1,
                                        emb, ag, bjp, hw1);
    k_gcn1<<<N_NODES, 256, 0, stream>>>(hw1, dself, rowptr, csrc, cnrm, bc1, g1, be1, Wc2, hw2);
    k_gcn2<<<N_NODES, 256, 0, stream>>>(hw2, dself, rowptr, csrc, cnrm, bc2, g2, be2, Wout, bout,
                                        (float*)d_out);
    dim3 sg(N_NODES/64, N_NODES/16);
    k_scores<<<sg, 256, 0, stream>>>(ag, bjp, Wi2, bi2, (float*)d_out + N_NODES*OUT_F);
}

// Round 4
// 218.829 us; speedup vs baseline: 1.2135x; 1.0590x over previous
//
#include <hip/hip_runtime.h>
#include <math.h>

#define N_NODES 2048
#define N_EDGES 65536
#define SEQL 5
#define IN_F 32
#define HID 64
#define OUT_F 16
#define LN_EPS 1e-5f

// ---------------- degree + in-edge count scatter ----------------
__global__ void k_deg(const int* __restrict__ ei, const float* __restrict__ ew,
                      float* __restrict__ deg, int* __restrict__ cnt){
    int e = blockIdx.x * 256 + threadIdx.x;
    if (e < N_EDGES){
        int d = ei[N_EDGES + e];
        atomicAdd(&deg[d], ew[e]);
        atomicAdd(&cnt[d], 1);
    }
}

// ---------------- dinv/dself + rowptr scan + combined gate weights ----------------
__global__ void k_scan_wcomb(const float* __restrict__ deg, const int* __restrict__ cnt,
                             float* __restrict__ dinv, float* __restrict__ dself, int* __restrict__ rowptr,
                             const float* __restrict__ Wcz, const float* __restrict__ Wlz,
                             const float* __restrict__ bcz, const float* __restrict__ blz,
                             const float* __restrict__ Wch, const float* __restrict__ Wlh,
                             const float* __restrict__ bch, const float* __restrict__ blh,
                             float* __restrict__ Wzp, float* __restrict__ Whp, float* __restrict__ bUV){
    int b = blockIdx.x, t = threadIdx.x;
    if (b == 0){
        __shared__ int s[1024];
        int n0 = 2*t, n1 = 2*t + 1;
        float d0 = deg[n0] + 1.f, d1 = deg[n1] + 1.f;
        float i0 = 1.f / sqrtf(d0), i1 = 1.f / sqrtf(d1);
        dinv[n0] = i0; dinv[n1] = i1;
        dself[n0] = i0*i0; dself[n1] = i1*i1;
        int a0 = cnt[n0], a1 = cnt[n1];
        s[t] = a0 + a1;
        __syncthreads();
        for (int off = 1; off < 1024; off <<= 1){
            int v = (t >= off) ? s[t - off] : 0;
            __syncthreads();
            s[t] += v;
            __syncthreads();
        }
        int pe = (t == 0) ? 0 : s[t-1];
        rowptr[n0] = pe;
        rowptr[n1] = pe + a0;
        if (t == 1023) rowptr[2048] = s[1023];
    } else {
        const float* Wc = (b == 1) ? Wcz : Wch;
        const float* Wl = (b == 1) ? Wlz : Wlh;
        const float* bc = (b == 1) ? bcz : bch;
        const float* bl = (b == 1) ? blz : blh;
        float* Wp = (b == 1) ? Wzp : Whp;
        for (int idx = t; idx < IN_F*HID; idx += 1024){
            int i = idx >> 6, f = idx & 63;
            float s = 0.f;
            for (int k = 0; k < HID; ++k) s += Wc[i*HID+k] * Wl[k*HID+f];
            Wp[idx] = s;
        }
        if (t < HID){
            float s = bl[t];
            for (int k = 0; k < HID; ++k) s += bc[k] * Wl[k*HID+t];
            bUV[(b-1)*HID + t] = s;
        }
    }
}

// ---------------- CSR fill + per-edge norm ----------------
__global__ void k_csr(const int* __restrict__ ei, const float* __restrict__ ew,
                      const float* __restrict__ dinv, const int* __restrict__ rowptr,
                      int* __restrict__ fill, int* __restrict__ csrc, float* __restrict__ cnrm){
    int e = blockIdx.x * 256 + threadIdx.x;
    if (e < N_EDGES){
        int s = ei[e], d = ei[N_EDGES + e];
        int pos = rowptr[d] + atomicAdd(&fill[d], 1);
        csrc[pos] = s;
        cnrm[pos] = dinv[s] * ew[e] * dinv[d];
    }
}

// ---------------- aggX[n][t][f<32] = sum_edges cnrm*x[t,src,f] + dself*x[t,n,f] ----------------
// Aggregate the 32-wide INPUT (not the 128-wide gate pre-activations): 4x less gather
// traffic, and x (1.3 MB) is L2-resident on every XCD.
__global__ __launch_bounds__(256) void k_aggx(const float* __restrict__ x, const float* __restrict__ dself,
        const int* __restrict__ rowptr, const int* __restrict__ csrc, const float* __restrict__ cnrm,
        float* __restrict__ aggX){
    int n = blockIdx.x;
    int tid = threadIdx.x;
    int slot = tid >> 5, f = tid & 31;         // 8 edge slots x 32 features
    __shared__ float part[8][SEQL][IN_F];
    float acc[SEQL] = {0.f, 0.f, 0.f, 0.f, 0.f};
    int beg = rowptr[n], end = rowptr[n+1];
    for (int p = beg + slot; p < end; p += 8){
        int s = csrc[p]; float c = cnrm[p];
        #pragma unroll
        for (int t = 0; t < SEQL; ++t)
            acc[t] += c * x[(t*N_NODES + s)*IN_F + f];
    }
    #pragma unroll
    for (int t = 0; t < SEQL; ++t) part[slot][t][f] = acc[t];
    __syncthreads();
    if (tid < SEQL*IN_F){
        int t = tid >> 5, ff = tid & 31;
        float s = dself[n] * x[(t*N_NODES + n)*IN_F + ff];
        #pragma unroll
        for (int sl = 0; sl < 8; ++sl) s += part[sl][t][ff];
        aggX[n*(SEQL*IN_F) + tid] = s;
    }
}

// ---------------- fused: (aggX @ Wzp/Whp + b) -> gates -> Wred -> emb -> 3 products ----------------
__global__ __launch_bounds__(320) void k_gate2(const float* __restrict__ aggX, const float* __restrict__ bUV,
        const float* __restrict__ Wzp, const float* __restrict__ Whp,
        const float* __restrict__ Wred, const float* __restrict__ bred,
        const float* __restrict__ Wi1, const float* __restrict__ bi1, const float* __restrict__ Wc1,
        float* __restrict__ emb, float* __restrict__ ag, float* __restrict__ bjp,
        float* __restrict__ hw1){
    int n = blockIdx.x;
    int f = threadIdx.x & 63;
    int t = threadIdx.x >> 6;                  // wave = timestep
    __shared__ float axs[SEQL][IN_F];
    __shared__ float hs[SEQL][HID];
    __shared__ float part[SEQL][HID];
    if (threadIdx.x < SEQL*IN_F) ((float*)axs)[threadIdx.x] = aggX[n*(SEQL*IN_F) + threadIdx.x];
    __syncthreads();
    float zz = bUV[f], hh = bUV[HID + f];
    #pragma unroll
    for (int i = 0; i < IN_F; ++i){
        float a = axs[t][i];                   // wave-uniform LDS broadcast
        zz += a * Wzp[i*HID + f];
        hh += a * Whp[i*HID + f];
    }
    float z = 1.f / (1.f + expf(-zz));
    hs[t][f] = (1.f - z) * tanhf(hh);
    __syncthreads();
    float pp = 0.f;
    #pragma unroll
    for (int k = 0; k < HID; ++k) pp += hs[t][k] * Wred[(t*HID + k)*HID + f];
    part[t][f] = pp;
    __syncthreads();
    if (t == 0){
        float hred = bred[f] + part[0][f] + part[1][f] + part[2][f] + part[3][f] + part[4][f];
        emb[n*HID + f] = hred;
        hs[0][f] = hred;
    }
    __syncthreads();
    if (t < 3){
        const float* W = (t == 0) ? Wi1 : (t == 1) ? (Wi1 + HID*HID) : Wc1;
        float acc = (t == 1) ? bi1[f] : 0.f;
        #pragma unroll
        for (int k = 0; k < HID; ++k) acc += hs[0][k] * W[k*HID + f];
        float* O = (t == 0) ? ag : (t == 1) ? bjp : hw1;
        O[n*HID + f] = acc;                    // bjp has bi1 folded in
    }
}

// ---------------- gcn1: 4 waves split edges, LN+relu, premultiply Wc2 ----------------
__global__ __launch_bounds__(256) void k_gcn1(
                       const float* __restrict__ hw1, const float* __restrict__ dself,
                       const int* __restrict__ rowptr, const int* __restrict__ csrc, const float* __restrict__ cnrm,
                       const float* __restrict__ bc1, const float* __restrict__ g1, const float* __restrict__ be1,
                       const float* __restrict__ Wc2, float* __restrict__ hw2){
    int n = blockIdx.x;
    int f = threadIdx.x & 63;
    int w = threadIdx.x >> 6;              // 0..3
    int beg = rowptr[n], end = rowptr[n+1];
    __shared__ float red[4][HID];
    __shared__ float hsh[HID];
    float agg = 0.f;
    for (int p = beg + w; p < end; p += 4) agg += cnrm[p] * hw1[csrc[p]*HID + f];
    red[w][f] = agg;
    __syncthreads();
    if (w == 0){
        float g = red[0][f] + red[1][f] + red[2][f] + red[3][f]
                + dself[n] * hw1[n*HID + f] + bc1[f];
        float sum = g;
        for (int o = 32; o > 0; o >>= 1) sum += __shfl_xor(sum, o, 64);
        float mu = sum * (1.f/64.f);
        float d = g - mu;
        float vs = d * d;
        for (int o = 32; o > 0; o >>= 1) vs += __shfl_xor(vs, o, 64);
        float var = vs * (1.f/64.f);
        float h = d * (1.f / sqrtf(var + LN_EPS)) * g1[f] + be1[f];
        hsh[f] = fmaxf(h, 0.f);
    }
    __syncthreads();
    float s = 0.f;
    #pragma unroll
    for (int k = 0; k < 16; ++k) s += hsh[w*16 + k] * Wc2[(w*16 + k)*HID + f];
    red[w][f] = s;
    __syncthreads();
    if (w == 0) hw2[n*HID + f] = red[0][f] + red[1][f] + red[2][f] + red[3][f];
}

// ---------------- gcn2: 4 waves split edges, LN+relu, node_pred out ----------------
__global__ __launch_bounds__(256) void k_gcn2(
                       const float* __restrict__ hw2, const float* __restrict__ dself,
                       const int* __restrict__ rowptr, const int* __restrict__ csrc, const float* __restrict__ cnrm,
                       const float* __restrict__ bc2, const float* __restrict__ g2, const float* __restrict__ be2,
                       const float* __restrict__ Wout, const float* __restrict__ bout, float* __restrict__ outp){
    int n = blockIdx.x;
    int f = threadIdx.x & 63;
    int w = threadIdx.x >> 6;
    int beg = rowptr[n], end = rowptr[n+1];
    __shared__ float red[4][HID];
    __shared__ float hsh[HID];
    float agg = 0.f;
    for (int p = beg + w; p < end; p += 4) agg += cnrm[p] * hw2[csrc[p]*HID + f];
    red[w][f] = agg;
    __syncthreads();
    if (w == 0){
        float g = red[0][f] + red[1][f] + red[2][f] + red[3][f]
                + dself[n] * hw2[n*HID + f] + bc2[f];
        float sum = g;
        for (int o = 32; o > 0; o >>= 1) sum += __shfl_xor(sum, o, 64);
        float mu = sum * (1.f/64.f);
        float d = g - mu;
        float vs = d * d;
        for (int o = 32; o > 0; o >>= 1) vs += __shfl_xor(vs, o, 64);
        float var = vs * (1.f/64.f);
        float h = d * (1.f / sqrtf(var + LN_EPS)) * g2[f] + be2[f];
        hsh[f] = fmaxf(h, 0.f);
    }
    __syncthreads();
    if (w == 0 && f < OUT_F){
        float s = bout[f];
        #pragma unroll
        for (int k = 0; k < HID; ++k) s += hsh[k] * Wout[k*OUT_F + f];
        outp[n*OUT_F + f] = s;
    }
}

// ---------------- scores[i,j] = sum_f relu(a_i + bj_j)_f * Wi2_f + bi2 ----------------
__global__ __launch_bounds__(256) void k_scores(const float* __restrict__ ag, const float* __restrict__ bjp,
                         const float* __restrict__ Wi2, const float* __restrict__ bi2,
                         float* __restrict__ outs){
    __shared__ __align__(16) float bs[64][68];   // stride 68 floats = 17 float4s: conflict-free b128
    __shared__ __align__(16) float as[16][68];
    __shared__ __align__(16) float wv[64];
    int tid = threadIdx.x;
    int j0 = blockIdx.x * 64;
    int i0 = blockIdx.y * 16;
    for (int idx = tid; idx < 1024; idx += 256){           // 64 rows x 16 float4 chunks
        int jj = idx >> 4, c = idx & 15;
        float4 v = *(const float4*)&bjp[(j0 + jj)*HID + c*4];
        *(float4*)&bs[jj][c*4] = v;
    }
    {   int ii = tid >> 4, c = tid & 15;                   // 16 rows x 16 chunks = 256
        float4 v = *(const float4*)&ag[(i0 + ii)*HID + c*4];
        *(float4*)&as[ii][c*4] = v;
    }
    if (tid < 64) wv[tid] = Wi2[tid];
    __syncthreads();
    int tj = tid & 63;
    int w = tid >> 6;
    float bi2v = bi2[0];
    float acc0 = 0.f, acc1 = 0.f, acc2 = 0.f, acc3 = 0.f;
    #pragma unroll
    for (int c = 0; c < 16; ++c){
        float4 bv = *(float4*)&bs[tj][c*4];
        float4 w4 = *(float4*)&wv[c*4];
        float4 a0 = *(float4*)&as[w*4 + 0][c*4];
        float4 a1 = *(float4*)&as[w*4 + 1][c*4];
        float4 a2 = *(float4*)&as[w*4 + 2][c*4];
        float4 a3 = *(float4*)&as[w*4 + 3][c*4];
        acc0 += fmaxf(a0.x+bv.x,0.f)*w4.x + fmaxf(a0.y+bv.y,0.f)*w4.y
              + fmaxf(a0.z+bv.z,0.f)*w4.z + fmaxf(a0.w+bv.w,0.f)*w4.w;
        acc1 += fmaxf(a1.x+bv.x,0.f)*w4.x + fmaxf(a1.y+bv.y,0.f)*w4.y
              + fmaxf(a1.z+bv.z,0.f)*w4.z + fmaxf(a1.w+bv.w,0.f)*w4.w;
        acc2 += fmaxf(a2.x+bv.x,0.f)*w4.x + fmaxf(a2.y+bv.y,0.f)*w4.y
              + fmaxf(a2.z+bv.z,0.f)*w4.z + fmaxf(a2.w+bv.w,0.f)*w4.w;
        acc3 += fmaxf(a3.x+bv.x,0.f)*w4.x + fmaxf(a3.y+bv.y,0.f)*w4.y
              + fmaxf(a3.z+bv.z,0.f)*w4.z + fmaxf(a3.w+bv.w,0.f)*w4.w;
    }
    long ro = (long)(i0 + w*4) * N_NODES + j0 + tj;
    outs[ro                ] = acc0 + bi2v;
    outs[ro +     N_NODES  ] = acc1 + bi2v;
    outs[ro + 2L* N_NODES  ] = acc2 + bi2v;
    outs[ro + 3L* N_NODES  ] = acc3 + bi2v;
}

extern "C" void kernel_launch(void* const* d_in, const int* in_sizes, int n_in,
                              void* d_out, int out_size, void* d_ws, size_t ws_size,
                              hipStream_t stream){
    const float* x   = (const float*)d_in[0];
    const float* ew  = (const float*)d_in[1];
    const float* Wcz = (const float*)d_in[2];  const float* bcz = (const float*)d_in[3];
    const float* Wlz = (const float*)d_in[4];  const float* blz = (const float*)d_in[5];
    // d_in[6..9]: Wcr/bcr/Wlr/blr — dead code (H=0 so reset gate has no effect)
    const float* Wch = (const float*)d_in[10]; const float* bch = (const float*)d_in[11];
    const float* Wlh = (const float*)d_in[12]; const float* blh = (const float*)d_in[13];
    const float* Wred= (const float*)d_in[14]; const float* bred= (const float*)d_in[15];
    const float* Wc1 = (const float*)d_in[16]; const float* bc1 = (const float*)d_in[17];
    const float* Wc2 = (const float*)d_in[18]; const float* bc2 = (const float*)d_in[19];
    const float* g1  = (const float*)d_in[20]; const float* be1 = (const float*)d_in[21];
    const float* g2  = (const float*)d_in[22]; const float* be2 = (const float*)d_in[23];
    const float* Wout= (const float*)d_in[24]; const float* bout= (const float*)d_in[25];
    const float* Wi1 = (const float*)d_in[26]; const float* bi1 = (const float*)d_in[27];
    const float* Wi2 = (const float*)d_in[28]; const float* bi2 = (const float*)d_in[29];
    const int*  ei  = (const int*)d_in[30];

    char* w = (char*)d_ws;
    float* deg    = (float*)(w + 0);        // 2048 f
    int*   cnt    = (int*)  (w + 8192);     // 2048 i
    int*   fill   = (int*)  (w + 16384);    // 2048 i   [first 24576 B memset to 0]
    int*   rowptr = (int*)  (w + 24576);    // 2049 i
    float* dinv   = (float*)(w + 36864);
    float* dself  = (float*)(w + 45056);
    int*   csrc   = (int*)  (w + 53248);    // E ints
    float* cnrm   = (float*)(w + 315392);   // E floats
    float* Wzp    = (float*)(w + 577536);   // 32*64
    float* Whp    = (float*)(w + 585728);   // 32*64
    float* bUV    = (float*)(w + 593920);   // 128
    float* aggX   = (float*)(w + 595968);   // 2048*160 f = 1.31 MB
    float* emb    = (float*)(w + 1906688);  // N*64 each:
    float* ag     = emb + N_NODES*HID;
    float* bjp    = ag  + N_NODES*HID;
    float* hw1    = bjp + N_NODES*HID;
    float* hw2    = hw1 + N_NODES*HID;

    hipMemsetAsync(d_ws, 0, 24576, stream);
    k_deg<<<N_EDGES/256, 256, 0, stream>>>(ei, ew, deg, cnt);
    k_scan_wcomb<<<3, 1024, 0, stream>>>(deg, cnt, dinv, dself, rowptr,
                                         Wcz, Wlz, bcz, blz, Wch, Wlh, bch, blh,
                                         Wzp, Whp, bUV);
    k_csr<<<N_EDGES/256, 256, 0, stream>>>(ei, ew, dinv, rowptr, fill, csrc, cnrm);
    k_aggx<<<N_NODES, 256, 0, stream>>>(x, dself, rowptr, csrc, cnrm, aggX);
    k_gate2<<<N_NODES, 320, 0, stream>>>(aggX, bUV, Wzp, Whp, Wred, bred, Wi1, bi1, Wc1,
                                         emb, ag, bjp, hw1);
    k_gcn1<<<N_NODES, 256, 0, stream>>>(hw1, dself, rowptr, csrc, cnrm, bc1, g1, be1, Wc2, hw2);
    k_gcn2<<<N_NODES, 256, 0, stream>>>(hw2, dself, rowptr, csrc, cnrm, bc2, g2, be2, Wout, bout,
                                        (float*)d_out);
    dim3 sg(N_NODES/64, N_NODES/16);
    k_scores<<<sg, 256, 0, stream>>>(ag, bjp, Wi2, bi2, (float*)d_out + N_NODES*OUT_F);
}